// Round 5
// baseline (15685.506 us; speedup 1.0000x reference)
//
#include <hip/hip_runtime.h>
#include <hip/hip_bf16.h>
#include <hip/hip_cooperative_groups.h>

namespace cg = cooperative_groups;

// Problem constants
#define B 128
#define T 256
#define E 300
#define HH 256
#define O 5
#define NSTEP (2*T - 1)   // 511
#define NINT 255          // internal (reduce) nodes per batch
#define NG 8              // nodes per group (weight amortization factor)
#define PSTR 41           // padded partial stride (40 values + 1)
#define MAXBLK 1024       // cooperative grid upper bound (4 blocks/CU)

__device__ __forceinline__ float sigm(float x) { return 1.f / (1.f + __expf(-x)); }

// ---------------------------------------------------------------------------
// K0: transpose weights.
//   WcT[e][0:256] = Wp[h][e], WcT[e][256:512] = Wg[h][e]
//   WrT[k][j] = Wr[j][k]  (j in [0,1280), k in [0,512)) -- k-major, coalesced per-k
// ---------------------------------------------------------------------------
__global__ __launch_bounds__(256) void k_transpose(
    const float* __restrict__ Wp, const float* __restrict__ Wg,
    const float* __restrict__ Wr, float* __restrict__ WcT,
    float* __restrict__ WrT) {
  int idx = blockIdx.x * 256 + threadIdx.x;
  if (idx < HH * E) {
    int h = idx / E;
    int e = idx % E;
    WcT[e * 512 + h]       = Wp[idx];
    WcT[e * 512 + 256 + h] = Wg[idx];
  }
  if (idx < 5 * HH * 2 * HH) {   // 1280*512
    int j = idx / 512;
    int k = idx % 512;
    WrT[k * 1280 + j] = Wr[idx];
  }
}

// ---------------------------------------------------------------------------
// K1: leaf states. buffers[b][t][0:256]=h, [256:512]=c
// ---------------------------------------------------------------------------
#define TT 16
__global__ __launch_bounds__(256) void k_buffers(
    const int* __restrict__ x_ids, const float* __restrict__ embed,
    const float* __restrict__ WcT, const float* __restrict__ bp,
    const float* __restrict__ bg, float* __restrict__ buffers) {
  __shared__ float lds[TT * E];
  const int b  = blockIdx.y;
  const int t0 = blockIdx.x * TT;
  const int tid = threadIdx.x;

  for (int i = tid; i < TT * E; i += 256) {
    int t = i / E;
    int e = i % E;
    int id = x_ids[b * T + t0 + t];
    lds[i] = embed[(size_t)id * E + e];
  }
  __syncthreads();

  const int h = tid;
  float accP[TT], accG[TT];
#pragma unroll
  for (int t = 0; t < TT; ++t) { accP[t] = bp[h]; accG[t] = bg[h]; }

  for (int e = 0; e < E; ++e) {
    float wp = WcT[e * 512 + h];
    float wg = WcT[e * 512 + 256 + h];
#pragma unroll
    for (int t = 0; t < TT; ++t) {
      float x = lds[t * E + e];
      accP[t] = fmaf(x, wp, accP[t]);
      accG[t] = fmaf(x, wg, accG[t]);
    }
  }

#pragma unroll
  for (int t = 0; t < TT; ++t) {
    float c  = accP[t];
    float hb = tanhf(c) * sigm(accG[t]);
    size_t base = ((size_t)b * T + t0 + t) * 512;
    buffers[base + h]       = hb;
    buffers[base + 256 + h] = c;
  }
}

// ---------------------------------------------------------------------------
// K2: prep — simulate shift/reduce per batch element, assign tree levels,
// build level-ordered worklist. 1 block, 128 threads (one per batch elem).
// meta[b][r] = left | right<<9 | level<<18   (node id = 256+r)
// ---------------------------------------------------------------------------
__global__ __launch_bounds__(128) void k_prep(
    const int* __restrict__ trans, int* __restrict__ meta,
    int* __restrict__ levCnt, int* __restrict__ levOff, int* __restrict__ maxLevG,
    int* __restrict__ rootA, unsigned* __restrict__ worklist,
    unsigned short* __restrict__ stkG) {
  __shared__ int cnt[256];
  __shared__ int off[256];
  __shared__ int cur[256];
  const int b = threadIdx.x;
  for (int i = b; i < 256; i += 128) cnt[i] = 0;
  __syncthreads();

  int sp = 0, bp = T, r = 0;
  for (int s = 0; s < NSTEP; ++s) {
    int tr = trans[s * B + b];
    if (tr == 0) {                       // SHIFT: leaf id = bp-1, level 0
      stkG[sp * 128 + b] = (unsigned short)(bp - 1);
      sp++; bp--;
    } else {                             // REDUCE
      int idR = stkG[(sp - 1) * 128 + b];
      int idL = stkG[(sp - 2) * 128 + b];
      sp -= 2;
      int lL = (idL < 256) ? 0 : (meta[b * NINT + idL - 256] >> 18);
      int lR = (idR < 256) ? 0 : (meta[b * NINT + idR - 256] >> 18);
      int lev = max(lL, lR) + 1;
      meta[b * NINT + r] = idL | (idR << 9) | (lev << 18);
      atomicAdd(&cnt[lev], 1);
      stkG[sp * 128 + b] = (unsigned short)(256 + r);
      sp++; r++;
    }
  }
  rootA[b] = (int)stkG[0 * 128 + b];
  __syncthreads();

  if (b == 0) {
    int acc = 0, ml = 1;
    for (int l = 0; l < 256; ++l) {
      off[l] = acc; acc += cnt[l];
      if (cnt[l] > 0) ml = l;
    }
    *maxLevG = ml;
  }
  __syncthreads();
  for (int i = b; i < 256; i += 128) { levCnt[i] = cnt[i]; levOff[i] = off[i]; cur[i] = off[i]; }
  __syncthreads();

  for (int i = 0; i < NINT; ++i) {
    int lev = meta[b * NINT + i] >> 18;
    int pos = atomicAdd(&cur[lev], 1);
    worklist[pos] = (unsigned)((b << 9) | (256 + i));
  }
}

// ---------------------------------------------------------------------------
// K3: level-parallel TreeLSTM cells (cooperative, latency-tolerant rewrite).
// Work item = (group of NG=8 nodes, 64-wide h-slice). 256 threads:
//   hcol = tid&63 : output column h0+hcol (same column for all 5 gates)
//   kq   = tid>>6 : k-quarter [kq*128, kq*128+128)
// Per item: stage x=[hl|hr] (8x512 f32) into LDS (coalesced), then each thread
// accumulates acc[5 gates][8 nodes] over its k-quarter reading weights
// coalesced from WrT[k][g*256+h0+hcol] and x via broadcast ds_read_b128.
// k-partials reduced via LDS; kq==0 threads apply activations and write.
// ---------------------------------------------------------------------------
__global__ __launch_bounds__(256, 4) void k_tree(
    const float* __restrict__ WrT, const float* __restrict__ br,
    const int* __restrict__ meta, const int* __restrict__ levCnt,
    const int* __restrict__ levOff, const int* __restrict__ maxLevG,
    const unsigned* __restrict__ worklist,
    const float* __restrict__ buffers, float* __restrict__ internal) {
  cg::grid_group grid = cg::this_grid();
  __shared__ float smem[3 * 64 * PSTR];   // 7872 f32 = 31.5KB; unioned x/partials
  float* xs = smem;                        // [NG][512] (16KB) during FMA phase
  float* part = smem;                      // [3][64][PSTR] during reduce phase

  const int tid  = threadIdx.x;
  const int hcol = tid & 63;
  const int kq   = tid >> 6;
  const int maxLev = *maxLevG;

  for (int lev = 1; lev <= maxLev; ++lev) {
    const int cnt  = levCnt[lev];
    const int woff = levOff[lev];
    const int ngrp = (cnt + NG - 1) / NG;
    const int items = ngrp << 2;           // 4 h-slices per group

    for (int item = blockIdx.x; item < items; item += gridDim.x) {
      const int grp = item >> 2;
      const int h0  = (item & 3) << 6;
      __syncthreads();   // prior item's LDS reads complete before restage

      // --- node meta (wave-uniform -> SGPR) ---
      const float* xlp[NG];
      const float* xrp[NG];
      float* dstp[NG];
#pragma unroll
      for (int n = 0; n < NG; ++n) {
        int wi = woff + grp * NG + n;
        if (wi >= woff + cnt) wi = woff + cnt - 1;   // pad: duplicate last node
        unsigned w = worklist[wi];
        int node = __builtin_amdgcn_readfirstlane((int)(w & 511u));
        int bb   = __builtin_amdgcn_readfirstlane((int)(w >> 9));
        int m    = __builtin_amdgcn_readfirstlane(meta[bb * NINT + node - 256]);
        int il = m & 511, ir = (m >> 9) & 511;
        xlp[n] = (il < 256) ? (buffers + (((size_t)bb * T + il) << 9))
                            : (internal + (((size_t)bb * NINT + il - 256) << 9));
        xrp[n] = (ir < 256) ? (buffers + (((size_t)bb * T + ir) << 9))
                            : (internal + (((size_t)bb * NINT + ir - 256) << 9));
        dstp[n] = internal + (((size_t)bb * NINT + node - 256) << 9);
      }

      // --- stage x = [hl | hr] into LDS (coalesced dword loads) ---
#pragma unroll
      for (int n = 0; n < NG; ++n) {
        xs[n * 512 + tid]       = xlp[n][tid];
        xs[n * 512 + 256 + tid] = xrp[n][tid];
      }
      __syncthreads();

      // --- FMA over this thread's k-quarter ---
      float acc[5][NG];
#pragma unroll
      for (int g = 0; g < 5; ++g)
#pragma unroll
        for (int n = 0; n < NG; ++n) acc[g][n] = 0.f;

      const float* wb = WrT + h0 + hcol;   // + k*1280 + g*256
      const int kend = (kq << 7) + 128;
      for (int k0 = kq << 7; k0 < kend; k0 += 4) {
        float4 xv[NG];
#pragma unroll
        for (int n = 0; n < NG; ++n)
          xv[n] = *(const float4*)&xs[n * 512 + k0];   // broadcast ds_read_b128
        const float* wk = wb + (size_t)k0 * 1280;
#pragma unroll
        for (int kk = 0; kk < 4; ++kk) {
          const float* wp = wk + (size_t)kk * 1280;
          float w0 = wp[0], w1 = wp[256], w2 = wp[512], w3 = wp[768], w4 = wp[1024];
#pragma unroll
          for (int n = 0; n < NG; ++n) {
            float xval = (kk == 0) ? xv[n].x : (kk == 1) ? xv[n].y
                       : (kk == 2) ? xv[n].z : xv[n].w;
            acc[0][n] = fmaf(w0, xval, acc[0][n]);
            acc[1][n] = fmaf(w1, xval, acc[1][n]);
            acc[2][n] = fmaf(w2, xval, acc[2][n]);
            acc[3][n] = fmaf(w3, xval, acc[3][n]);
            acc[4][n] = fmaf(w4, xval, acc[4][n]);
          }
        }
      }
      __syncthreads();   // xs reads done; smem becomes partial buffer

      // --- k-split reduce: kq>=1 deposit partials ---
      if (kq >= 1) {
        float* pp = part + (kq - 1) * (64 * PSTR) + hcol * PSTR;
#pragma unroll
        for (int g = 0; g < 5; ++g)
#pragma unroll
          for (int n = 0; n < NG; ++n) pp[g * NG + n] = acc[g][n];
      }
      __syncthreads();

      // --- combine: kq==0 threads finish their column for all 8 nodes ---
      if (kq == 0) {
        const int habs = h0 + hcol;
#pragma unroll
        for (int n = 0; n < NG; ++n) {
          float p[5];
#pragma unroll
          for (int g = 0; g < 5; ++g) {
            int pi = hcol * PSTR + g * NG + n;
            p[g] = acc[g][n]
                 + part[0 * (64 * PSTR) + pi]
                 + part[1 * (64 * PSTR) + pi]
                 + part[2 * (64 * PSTR) + pi]
                 + br[g * 256 + habs];
          }
          float cl = xlp[n][256 + habs];
          float cr = xrp[n][256 + habs];
          float ci  = sigm(p[0]);
          float cfl = sigm(p[1]);
          float cfr = sigm(p[2]);
          float tg  = tanhf(p[3]);
          float co  = sigm(p[4]);
          float cn  = ci * tg + cfl * cl + cfr * cr;
          float hn  = co * tanhf(cn);
          dstp[n][habs]       = hn;   // duplicate-pad rewrites same value: benign
          dstp[n][256 + habs] = cn;
        }
      }
    }
    __threadfence();
    grid.sync();
  }
}

// ---------------------------------------------------------------------------
// K4: logits = root_h @ Wo^T + bo
// ---------------------------------------------------------------------------
__global__ __launch_bounds__(256) void k_out(
    const float* __restrict__ Wo, const float* __restrict__ bo,
    const int* __restrict__ rootA, const float* __restrict__ buffers,
    const float* __restrict__ internal, float* __restrict__ out) {
  const int b = blockIdx.x;
  const int tid = threadIdx.x;
  __shared__ float red[256];
  int rid = rootA[b];
  const float* hsrc = (rid < 256) ? (buffers + (((size_t)b * T + rid) << 9))
                                  : (internal + (((size_t)b * NINT + rid - 256) << 9));
  float hj = hsrc[tid];
  for (int m = 0; m < O; ++m) {
    red[tid] = Wo[m * HH + tid] * hj;
    __syncthreads();
    for (int off = 128; off > 0; off >>= 1) {
      if (tid < off) red[tid] += red[tid + off];
      __syncthreads();
    }
    if (tid == 0) out[b * O + m] = red[0] + bo[m];
    __syncthreads();
  }
}

// ---------------------------------------------------------------------------
extern "C" void kernel_launch(void* const* d_in, const int* in_sizes, int n_in,
                              void* d_out, int out_size, void* d_ws, size_t ws_size,
                              hipStream_t stream) {
  const int*   x_ids = (const int*)d_in[0];
  const int*   trans = (const int*)d_in[1];
  const float* embed = (const float*)d_in[2];
  const float* Wp    = (const float*)d_in[3];
  const float* bp    = (const float*)d_in[4];
  const float* Wg    = (const float*)d_in[5];
  const float* bg    = (const float*)d_in[6];
  const float* Wr    = (const float*)d_in[7];
  const float* br    = (const float*)d_in[8];
  const float* Wo    = (const float*)d_in[9];
  const float* bo    = (const float*)d_in[10];
  float* out = (float*)d_out;

  float* ws       = (float*)d_ws;
  float* WcT      = ws;                                   // 300*512
  float* WrT      = WcT + 300 * 512;                      // 512*1280
  float* buffers  = WrT + 512 * 1280;                     // B*T*512
  float* internal = buffers + (size_t)B * T * 512;        // B*NINT*512
  int*   meta     = (int*)(internal + (size_t)B * NINT * 512);  // B*NINT
  int*   levCnt   = meta + B * NINT;                      // 256
  int*   levOff   = levCnt + 256;                         // 256
  int*   maxLevG  = levOff + 256;                         // 1
  int*   rootA    = maxLevG + 1;                          // B
  unsigned* worklist = (unsigned*)(rootA + B);            // B*NINT = 32640
  unsigned short* stkG = (unsigned short*)(worklist + B * NINT);  // 128*256 u16

  k_transpose<<<(5 * HH * 2 * HH + 255) / 256, 256, 0, stream>>>(Wp, Wg, Wr, WcT, WrT);
  k_buffers<<<dim3(T / TT, B), 256, 0, stream>>>(x_ids, embed, WcT, bp, bg, buffers);
  k_prep<<<1, 128, 0, stream>>>(trans, meta, levCnt, levOff, maxLevG, rootA, worklist, stkG);

  {
    // Cap cooperative grid at actual co-residency (avoid launch failure).
    int maxPerCU = 0;
    (void)hipOccupancyMaxActiveBlocksPerMultiprocessor(&maxPerCU, (const void*)k_tree, 256, 0);
    if (maxPerCU < 1) maxPerCU = 1;
    int nblk = maxPerCU * 256;
    if (nblk > MAXBLK) nblk = MAXBLK;
    void* args[] = {(void*)&WrT, (void*)&br, (void*)&meta, (void*)&levCnt, (void*)&levOff,
                    (void*)&maxLevG, (void*)&worklist, (void*)&buffers, (void*)&internal};
    hipLaunchCooperativeKernel((void*)k_tree, dim3(nblk), dim3(256), args, 0, stream);
  }

  k_out<<<B, 256, 0, stream>>>(Wo, bo, rootA, buffers, internal, out);
}

// Round 6
// 12813.818 us; speedup vs baseline: 1.2241x; 1.2241x over previous
//
#include <hip/hip_runtime.h>
#include <hip/hip_bf16.h>

// Problem constants
#define B 128
#define T 256
#define E 300
#define HH 256
#define O 5
#define NSTEP (2*T - 1)   // 511
#define NINT 255          // internal (reduce) nodes per batch
#define NG 8              // nodes per group (weight amortization factor)
#define PSTR 41           // padded partial stride (40 values + 1)
#define NBLK_TARGET 512   // 2 blocks/CU
#define BAR_STRIDE 16     // 64B per counter line
#define BAR_WORDS ((32 + 2) * BAR_STRIDE)

__device__ __forceinline__ float sigm(float x) { return 1.f / (1.f + __expf(-x)); }

// ---------------------------------------------------------------------------
// Hierarchical monotonic grid barrier.
// bar[s*16] s<32: sub-counters; bar[32*16]: root; bar[33*16]: generation.
// All counters monotonically increase; no resets -> no reset races.
// myN = 1-based barrier index. Requires gridDim.x % 32 == 0.
// ---------------------------------------------------------------------------
__device__ __forceinline__ void grid_barrier(unsigned* bar, int myN) {
  __syncthreads();                       // all threads done with level's work
  if (threadIdx.x == 0) {
    __threadfence();                     // release: internal[] writes visible
    const int per_sub = (int)(gridDim.x >> 5);
    const int s = (int)(blockIdx.x & 31);
    unsigned r = atomicAdd(&bar[s * BAR_STRIDE], 1u);
    if (r == (unsigned)(myN * per_sub - 1)) {          // last of subgroup
      unsigned q = atomicAdd(&bar[32 * BAR_STRIDE], 1u);
      if (q == (unsigned)(myN * 32 - 1)) {             // last subgroup
        atomicAdd(&bar[33 * BAR_STRIDE], 1u);          // gen = myN
      }
    }
    while (__hip_atomic_load(&bar[33 * BAR_STRIDE], __ATOMIC_ACQUIRE,
                             __HIP_MEMORY_SCOPE_AGENT) < (unsigned)myN) {
      __builtin_amdgcn_s_sleep(2);
    }
    __threadfence();                     // acquire: other blocks' writes
  }
  __syncthreads();
}

// ---------------------------------------------------------------------------
// K0: transpose weights.
//   WcT[e][0:256] = Wp[h][e], WcT[e][256:512] = Wg[h][e]
//   WrT[k][j] = Wr[j][k]  (j in [0,1280), k in [0,512)) -- k-major, coalesced per-k
// ---------------------------------------------------------------------------
__global__ __launch_bounds__(256) void k_transpose(
    const float* __restrict__ Wp, const float* __restrict__ Wg,
    const float* __restrict__ Wr, float* __restrict__ WcT,
    float* __restrict__ WrT) {
  int idx = blockIdx.x * 256 + threadIdx.x;
  if (idx < HH * E) {
    int h = idx / E;
    int e = idx % E;
    WcT[e * 512 + h]       = Wp[idx];
    WcT[e * 512 + 256 + h] = Wg[idx];
  }
  if (idx < 5 * HH * 2 * HH) {   // 1280*512
    int j = idx / 512;
    int k = idx % 512;
    WrT[k * 1280 + j] = Wr[idx];
  }
}

// ---------------------------------------------------------------------------
// K1: leaf states. buffers[b][t][0:256]=h, [256:512]=c
// ---------------------------------------------------------------------------
#define TT 16
__global__ __launch_bounds__(256) void k_buffers(
    const int* __restrict__ x_ids, const float* __restrict__ embed,
    const float* __restrict__ WcT, const float* __restrict__ bp,
    const float* __restrict__ bg, float* __restrict__ buffers) {
  __shared__ float lds[TT * E];
  const int b  = blockIdx.y;
  const int t0 = blockIdx.x * TT;
  const int tid = threadIdx.x;

  for (int i = tid; i < TT * E; i += 256) {
    int t = i / E;
    int e = i % E;
    int id = x_ids[b * T + t0 + t];
    lds[i] = embed[(size_t)id * E + e];
  }
  __syncthreads();

  const int h = tid;
  float accP[TT], accG[TT];
#pragma unroll
  for (int t = 0; t < TT; ++t) { accP[t] = bp[h]; accG[t] = bg[h]; }

  for (int e = 0; e < E; ++e) {
    float wp = WcT[e * 512 + h];
    float wg = WcT[e * 512 + 256 + h];
#pragma unroll
    for (int t = 0; t < TT; ++t) {
      float x = lds[t * E + e];
      accP[t] = fmaf(x, wp, accP[t]);
      accG[t] = fmaf(x, wg, accG[t]);
    }
  }

#pragma unroll
  for (int t = 0; t < TT; ++t) {
    float c  = accP[t];
    float hb = tanhf(c) * sigm(accG[t]);
    size_t base = ((size_t)b * T + t0 + t) * 512;
    buffers[base + h]       = hb;
    buffers[base + 256 + h] = c;
  }
}

// ---------------------------------------------------------------------------
// K2: prep — simulate shift/reduce per batch element, assign tree levels,
// build level-ordered worklist; zero the grid-barrier state.
// 1 block, 128 threads. meta[b][r] = left | right<<9 | level<<18
// ---------------------------------------------------------------------------
__global__ __launch_bounds__(128) void k_prep(
    const int* __restrict__ trans, int* __restrict__ meta,
    int* __restrict__ levCnt, int* __restrict__ levOff, int* __restrict__ maxLevG,
    int* __restrict__ rootA, unsigned* __restrict__ worklist,
    unsigned short* __restrict__ stkG, unsigned* __restrict__ bar) {
  __shared__ int cnt[256];
  __shared__ int off[256];
  __shared__ int cur[256];
  const int b = threadIdx.x;
  for (int i = b; i < 256; i += 128) cnt[i] = 0;
  for (int i = b; i < BAR_WORDS; i += 128) bar[i] = 0u;   // barrier init (ws re-poisoned)
  __syncthreads();

  int sp = 0, bp = T, r = 0;
  for (int s = 0; s < NSTEP; ++s) {
    int tr = trans[s * B + b];
    if (tr == 0) {                       // SHIFT: leaf id = bp-1, level 0
      stkG[sp * 128 + b] = (unsigned short)(bp - 1);
      sp++; bp--;
    } else {                             // REDUCE
      int idR = stkG[(sp - 1) * 128 + b];
      int idL = stkG[(sp - 2) * 128 + b];
      sp -= 2;
      int lL = (idL < 256) ? 0 : (meta[b * NINT + idL - 256] >> 18);
      int lR = (idR < 256) ? 0 : (meta[b * NINT + idR - 256] >> 18);
      int lev = max(lL, lR) + 1;
      meta[b * NINT + r] = idL | (idR << 9) | (lev << 18);
      atomicAdd(&cnt[lev], 1);
      stkG[sp * 128 + b] = (unsigned short)(256 + r);
      sp++; r++;
    }
  }
  rootA[b] = (int)stkG[0 * 128 + b];
  __syncthreads();

  if (b == 0) {
    int acc = 0, ml = 1;
    for (int l = 0; l < 256; ++l) {
      off[l] = acc; acc += cnt[l];
      if (cnt[l] > 0) ml = l;
    }
    *maxLevG = ml;
  }
  __syncthreads();
  for (int i = b; i < 256; i += 128) { levCnt[i] = cnt[i]; levOff[i] = off[i]; cur[i] = off[i]; }
  __syncthreads();

  for (int i = 0; i < NINT; ++i) {
    int lev = meta[b * NINT + i] >> 18;
    int pos = atomicAdd(&cur[lev], 1);
    worklist[pos] = (unsigned)((b << 9) | (256 + i));
  }
}

// ---------------------------------------------------------------------------
// K3: level-parallel TreeLSTM cells. Same compute as round 5 (validated);
// cg::grid.sync() replaced with the hierarchical custom barrier.
// Work item = (group of NG=8 nodes, 64-wide h-slice), 256 threads:
//   hcol = tid&63 : output column h0+hcol; kq = tid>>6 : k-quarter.
// ---------------------------------------------------------------------------
__global__ __launch_bounds__(256, 2) void k_tree(
    const float* __restrict__ WrT, const float* __restrict__ br,
    const int* __restrict__ meta, const int* __restrict__ levCnt,
    const int* __restrict__ levOff, const int* __restrict__ maxLevG,
    const unsigned* __restrict__ worklist,
    const float* __restrict__ buffers, float* __restrict__ internal,
    unsigned* __restrict__ bar) {
  __shared__ float smem[3 * 64 * PSTR];   // 31.5KB; unioned x / partials
  float* xs = smem;                        // [NG][512] during FMA phase
  float* part = smem;                      // [3][64][PSTR] during reduce phase

  const int tid  = threadIdx.x;
  const int hcol = tid & 63;
  const int kq   = tid >> 6;
  const int maxLev = *maxLevG;

  for (int lev = 1; lev <= maxLev; ++lev) {
    const int cnt  = levCnt[lev];
    const int woff = levOff[lev];
    const int ngrp = (cnt + NG - 1) / NG;
    const int items = ngrp << 2;           // 4 h-slices per group

    for (int item = blockIdx.x; item < items; item += gridDim.x) {
      const int grp = item >> 2;
      const int h0  = (item & 3) << 6;
      __syncthreads();   // prior item's LDS reads complete before restage

      // --- node meta (wave-uniform -> SGPR) ---
      const float* xlp[NG];
      const float* xrp[NG];
      float* dstp[NG];
#pragma unroll
      for (int n = 0; n < NG; ++n) {
        int wi = woff + grp * NG + n;
        if (wi >= woff + cnt) wi = woff + cnt - 1;   // pad: duplicate last node
        unsigned w = worklist[wi];
        int node = __builtin_amdgcn_readfirstlane((int)(w & 511u));
        int bb   = __builtin_amdgcn_readfirstlane((int)(w >> 9));
        int m    = __builtin_amdgcn_readfirstlane(meta[bb * NINT + node - 256]);
        int il = m & 511, ir = (m >> 9) & 511;
        xlp[n] = (il < 256) ? (buffers + (((size_t)bb * T + il) << 9))
                            : (internal + (((size_t)bb * NINT + il - 256) << 9));
        xrp[n] = (ir < 256) ? (buffers + (((size_t)bb * T + ir) << 9))
                            : (internal + (((size_t)bb * NINT + ir - 256) << 9));
        dstp[n] = internal + (((size_t)bb * NINT + node - 256) << 9);
      }

      // --- stage x = [hl | hr] into LDS (coalesced dword loads) ---
#pragma unroll
      for (int n = 0; n < NG; ++n) {
        xs[n * 512 + tid]       = xlp[n][tid];
        xs[n * 512 + 256 + tid] = xrp[n][tid];
      }
      __syncthreads();

      // --- FMA over this thread's k-quarter ---
      float acc[5][NG];
#pragma unroll
      for (int g = 0; g < 5; ++g)
#pragma unroll
        for (int n = 0; n < NG; ++n) acc[g][n] = 0.f;

      const float* wb = WrT + h0 + hcol;   // + k*1280 + g*256
      const int kend = (kq << 7) + 128;
      for (int k0 = kq << 7; k0 < kend; k0 += 4) {
        float4 xv[NG];
#pragma unroll
        for (int n = 0; n < NG; ++n)
          xv[n] = *(const float4*)&xs[n * 512 + k0];   // broadcast ds_read_b128
        const float* wk = wb + (size_t)k0 * 1280;
#pragma unroll
        for (int kk = 0; kk < 4; ++kk) {
          const float* wp = wk + (size_t)kk * 1280;
          float w0 = wp[0], w1 = wp[256], w2 = wp[512], w3 = wp[768], w4 = wp[1024];
#pragma unroll
          for (int n = 0; n < NG; ++n) {
            float xval = (kk == 0) ? xv[n].x : (kk == 1) ? xv[n].y
                       : (kk == 2) ? xv[n].z : xv[n].w;
            acc[0][n] = fmaf(w0, xval, acc[0][n]);
            acc[1][n] = fmaf(w1, xval, acc[1][n]);
            acc[2][n] = fmaf(w2, xval, acc[2][n]);
            acc[3][n] = fmaf(w3, xval, acc[3][n]);
            acc[4][n] = fmaf(w4, xval, acc[4][n]);
          }
        }
      }
      __syncthreads();   // xs reads done; smem becomes partial buffer

      // --- k-split reduce: kq>=1 deposit partials ---
      if (kq >= 1) {
        float* pp = part + (kq - 1) * (64 * PSTR) + hcol * PSTR;
#pragma unroll
        for (int g = 0; g < 5; ++g)
#pragma unroll
          for (int n = 0; n < NG; ++n) pp[g * NG + n] = acc[g][n];
      }
      __syncthreads();

      // --- combine: kq==0 threads finish their column for all 8 nodes ---
      if (kq == 0) {
        const int habs = h0 + hcol;
#pragma unroll
        for (int n = 0; n < NG; ++n) {
          float p[5];
#pragma unroll
          for (int g = 0; g < 5; ++g) {
            int pi = hcol * PSTR + g * NG + n;
            p[g] = acc[g][n]
                 + part[0 * (64 * PSTR) + pi]
                 + part[1 * (64 * PSTR) + pi]
                 + part[2 * (64 * PSTR) + pi]
                 + br[g * 256 + habs];
          }
          float cl = xlp[n][256 + habs];
          float cr = xrp[n][256 + habs];
          float ci  = sigm(p[0]);
          float cfl = sigm(p[1]);
          float cfr = sigm(p[2]);
          float tg  = tanhf(p[3]);
          float co  = sigm(p[4]);
          float cn  = ci * tg + cfl * cl + cfr * cr;
          float hn  = co * tanhf(cn);
          dstp[n][habs]       = hn;   // duplicate-pad rewrites same value: benign
          dstp[n][256 + habs] = cn;
        }
      }
    }
    grid_barrier(bar, lev);   // replaces __threadfence + cg::grid.sync
  }
}

// ---------------------------------------------------------------------------
// K4: logits = root_h @ Wo^T + bo
// ---------------------------------------------------------------------------
__global__ __launch_bounds__(256) void k_out(
    const float* __restrict__ Wo, const float* __restrict__ bo,
    const int* __restrict__ rootA, const float* __restrict__ buffers,
    const float* __restrict__ internal, float* __restrict__ out) {
  const int b = blockIdx.x;
  const int tid = threadIdx.x;
  __shared__ float red[256];
  int rid = rootA[b];
  const float* hsrc = (rid < 256) ? (buffers + (((size_t)b * T + rid) << 9))
                                  : (internal + (((size_t)b * NINT + rid - 256) << 9));
  float hj = hsrc[tid];
  for (int m = 0; m < O; ++m) {
    red[tid] = Wo[m * HH + tid] * hj;
    __syncthreads();
    for (int off = 128; off > 0; off >>= 1) {
      if (tid < off) red[tid] += red[tid + off];
      __syncthreads();
    }
    if (tid == 0) out[b * O + m] = red[0] + bo[m];
    __syncthreads();
  }
}

// ---------------------------------------------------------------------------
extern "C" void kernel_launch(void* const* d_in, const int* in_sizes, int n_in,
                              void* d_out, int out_size, void* d_ws, size_t ws_size,
                              hipStream_t stream) {
  const int*   x_ids = (const int*)d_in[0];
  const int*   trans = (const int*)d_in[1];
  const float* embed = (const float*)d_in[2];
  const float* Wp    = (const float*)d_in[3];
  const float* bp    = (const float*)d_in[4];
  const float* Wg    = (const float*)d_in[5];
  const float* bg    = (const float*)d_in[6];
  const float* Wr    = (const float*)d_in[7];
  const float* br    = (const float*)d_in[8];
  const float* Wo    = (const float*)d_in[9];
  const float* bo    = (const float*)d_in[10];
  float* out = (float*)d_out;

  float* ws       = (float*)d_ws;
  float* WcT      = ws;                                   // 300*512
  float* WrT      = WcT + 300 * 512;                      // 512*1280
  float* buffers  = WrT + 512 * 1280;                     // B*T*512
  float* internal = buffers + (size_t)B * T * 512;        // B*NINT*512
  int*   meta     = (int*)(internal + (size_t)B * NINT * 512);  // B*NINT
  int*   levCnt   = meta + B * NINT;                      // 256
  int*   levOff   = levCnt + 256;                         // 256
  int*   maxLevG  = levOff + 256;                         // 1
  int*   rootA    = maxLevG + 1;                          // B
  unsigned* worklist = (unsigned*)(rootA + B);            // B*NINT
  unsigned short* stkG = (unsigned short*)(worklist + B * NINT);  // 128*256 u16
  unsigned* bar   = (unsigned*)(stkG + 128 * 256);        // BAR_WORDS u32

  k_transpose<<<(5 * HH * 2 * HH + 255) / 256, 256, 0, stream>>>(Wp, Wg, Wr, WcT, WrT);
  k_buffers<<<dim3(T / TT, B), 256, 0, stream>>>(x_ids, embed, WcT, bp, bg, buffers);
  k_prep<<<1, 128, 0, stream>>>(trans, meta, levCnt, levOff, maxLevG, rootA, worklist,
                                stkG, bar);

  {
    // Co-residency-safe cooperative grid; must stay a multiple of 32 for the
    // hierarchical barrier's subgroup math.
    int maxPerCU = 0;
    (void)hipOccupancyMaxActiveBlocksPerMultiprocessor(&maxPerCU, (const void*)k_tree, 256, 0);
    if (maxPerCU < 1) maxPerCU = 1;
    int nblk = maxPerCU * 256;
    if (nblk > NBLK_TARGET) nblk = NBLK_TARGET;
    nblk &= ~31;
    if (nblk < 32) nblk = 32;
    void* args[] = {(void*)&WrT, (void*)&br, (void*)&meta, (void*)&levCnt, (void*)&levOff,
                    (void*)&maxLevG, (void*)&worklist, (void*)&buffers, (void*)&internal,
                    (void*)&bar};
    hipLaunchCooperativeKernel((void*)k_tree, dim3(nblk), dim3(256), args, 0, stream);
  }

  k_out<<<B, 256, 0, stream>>>(Wo, bo, rootA, buffers, internal, out);
}

// Round 8
// 3843.916 us; speedup vs baseline: 4.0806x; 3.3335x over previous
//
#include <hip/hip_runtime.h>
#include <hip/hip_bf16.h>

// Problem constants
#define B 128
#define T 256
#define E 300
#define HH 256
#define O 5
#define NSTEP (2*T - 1)   // 511
#define NINT 255          // internal (reduce) nodes per batch
#define NG 8              // nodes per group (weight amortization factor)
#define PSTR 41           // padded partial stride
#define LMAX_DIRECT 176   // per-level launches cover 1..176; catch-all covers rest
#define BAR_STRIDE 16
#define BAR_WORDS ((32 + 2) * BAR_STRIDE)

__device__ __forceinline__ float sigm(float x) { return 1.f / (1.f + __expf(-x)); }

// ---------------------------------------------------------------------------
// Hierarchical monotonic grid barrier (for the catch-all only; validated r6).
// ---------------------------------------------------------------------------
__device__ __forceinline__ void grid_barrier(unsigned* bar, int myN) {
  __syncthreads();
  if (threadIdx.x == 0) {
    __threadfence();
    const int per_sub = (int)(gridDim.x >> 5);
    const int s = (int)(blockIdx.x & 31);
    unsigned r = atomicAdd(&bar[s * BAR_STRIDE], 1u);
    if (r == (unsigned)(myN * per_sub - 1)) {
      unsigned q = atomicAdd(&bar[32 * BAR_STRIDE], 1u);
      if (q == (unsigned)(myN * 32 - 1)) {
        atomicAdd(&bar[33 * BAR_STRIDE], 1u);
      }
    }
    while (__hip_atomic_load(&bar[33 * BAR_STRIDE], __ATOMIC_ACQUIRE,
                             __HIP_MEMORY_SCOPE_AGENT) < (unsigned)myN) {
      __builtin_amdgcn_s_sleep(2);
    }
    __threadfence();
  }
  __syncthreads();
}

// ---------------------------------------------------------------------------
// K0: weight prep.
//   WcT[e][0:256] = Wp[h][e], WcT[e][256:512] = Wg[h][e]
//   W4: float4-tiled Wr^T:  W4[((k>>2)*1280 + j)*4 + (k&3)] = Wr[j][k]
//   -> thread loading column j, k-block k0 reads ONE coalesced float4.
// ---------------------------------------------------------------------------
__global__ __launch_bounds__(256) void k_transpose(
    const float* __restrict__ Wp, const float* __restrict__ Wg,
    const float* __restrict__ Wr, float* __restrict__ WcT,
    float* __restrict__ W4) {
  int idx = blockIdx.x * 256 + threadIdx.x;
  if (idx < HH * E) {
    int h = idx / E;
    int e = idx % E;
    WcT[e * 512 + h]       = Wp[idx];
    WcT[e * 512 + 256 + h] = Wg[idx];
  }
  if (idx < 5 * HH * 2 * HH) {   // 1280*512
    int j = idx / 512;
    int k = idx % 512;
    W4[((size_t)(k >> 2) * 1280 + j) * 4 + (k & 3)] = Wr[idx];
  }
}

// ---------------------------------------------------------------------------
// K1: leaf states. buffers[b][t][0:256]=h, [256:512]=c
// ---------------------------------------------------------------------------
#define TT 16
__global__ __launch_bounds__(256) void k_buffers(
    const int* __restrict__ x_ids, const float* __restrict__ embed,
    const float* __restrict__ WcT, const float* __restrict__ bp,
    const float* __restrict__ bg, float* __restrict__ buffers) {
  __shared__ float lds[TT * E];
  const int b  = blockIdx.y;
  const int t0 = blockIdx.x * TT;
  const int tid = threadIdx.x;

  for (int i = tid; i < TT * E; i += 256) {
    int t = i / E;
    int e = i % E;
    int id = x_ids[b * T + t0 + t];
    lds[i] = embed[(size_t)id * E + e];
  }
  __syncthreads();

  const int h = tid;
  float accP[TT], accG[TT];
#pragma unroll
  for (int t = 0; t < TT; ++t) { accP[t] = bp[h]; accG[t] = bg[h]; }

  for (int e = 0; e < E; ++e) {
    float wp = WcT[e * 512 + h];
    float wg = WcT[e * 512 + 256 + h];
#pragma unroll
    for (int t = 0; t < TT; ++t) {
      float x = lds[t * E + e];
      accP[t] = fmaf(x, wp, accP[t]);
      accG[t] = fmaf(x, wg, accG[t]);
    }
  }

#pragma unroll
  for (int t = 0; t < TT; ++t) {
    float c  = accP[t];
    float hb = tanhf(c) * sigm(accG[t]);
    size_t base = ((size_t)b * T + t0 + t) * 512;
    buffers[base + h]       = hb;
    buffers[base + 256 + h] = c;
  }
}

// ---------------------------------------------------------------------------
// K2: prep — levels + worklist + barrier init. 1 block, 128 threads.
// meta[b][r] = left | right<<9 | level<<18
// ---------------------------------------------------------------------------
__global__ __launch_bounds__(128) void k_prep(
    const int* __restrict__ trans, int* __restrict__ meta,
    int* __restrict__ levCnt, int* __restrict__ levOff, int* __restrict__ maxLevG,
    int* __restrict__ rootA, unsigned* __restrict__ worklist,
    unsigned short* __restrict__ stkG, unsigned* __restrict__ bar) {
  __shared__ int cnt[256];
  __shared__ int off[256];
  __shared__ int cur[256];
  const int b = threadIdx.x;
  for (int i = b; i < 256; i += 128) cnt[i] = 0;
  for (int i = b; i < BAR_WORDS; i += 128) bar[i] = 0u;
  __syncthreads();

  int sp = 0, bp = T, r = 0;
  for (int s = 0; s < NSTEP; ++s) {
    int tr = trans[s * B + b];
    if (tr == 0) {
      stkG[sp * 128 + b] = (unsigned short)(bp - 1);
      sp++; bp--;
    } else {
      int idR = stkG[(sp - 1) * 128 + b];
      int idL = stkG[(sp - 2) * 128 + b];
      sp -= 2;
      int lL = (idL < 256) ? 0 : (meta[b * NINT + idL - 256] >> 18);
      int lR = (idR < 256) ? 0 : (meta[b * NINT + idR - 256] >> 18);
      int lev = max(lL, lR) + 1;
      meta[b * NINT + r] = idL | (idR << 9) | (lev << 18);
      atomicAdd(&cnt[lev], 1);
      stkG[sp * 128 + b] = (unsigned short)(256 + r);
      sp++; r++;
    }
  }
  rootA[b] = (int)stkG[0 * 128 + b];
  __syncthreads();

  if (b == 0) {
    int acc = 0, ml = 1;
    for (int l = 0; l < 256; ++l) {
      off[l] = acc; acc += cnt[l];
      if (cnt[l] > 0) ml = l;
    }
    *maxLevG = ml;
  }
  __syncthreads();
  for (int i = b; i < 256; i += 128) { levCnt[i] = cnt[i]; levOff[i] = off[i]; cur[i] = off[i]; }
  __syncthreads();

  for (int i = 0; i < NINT; ++i) {
    int lev = meta[b * NINT + i] >> 18;
    int pos = atomicAdd(&cur[lev], 1);
    worklist[pos] = (unsigned)((b << 9) | (256 + i));
  }
}

// ---------------------------------------------------------------------------
// Level body (shared by k_level and k_catchall). Same structure as round 6
// (validated) but weights via coalesced float4 W4 layout.
// ---------------------------------------------------------------------------
__device__ __forceinline__ void do_level(
    int cnt, int woff,
    const float* __restrict__ W4, const float* __restrict__ br,
    const int* __restrict__ meta, const unsigned* __restrict__ worklist,
    const float* __restrict__ buffers, float* __restrict__ internal,
    float* smem) {
  float* xs = smem;     // [NG][512] during FMA phase
  float* part = smem;   // [3][64][PSTR] during reduce phase
  const int tid  = threadIdx.x;
  const int hcol = tid & 63;
  const int kq   = tid >> 6;

  const int ngrp = (cnt + NG - 1) / NG;
  const int items = ngrp << 2;

  for (int item = blockIdx.x; item < items; item += gridDim.x) {
    const int grp = item >> 2;
    const int h0  = (item & 3) << 6;
    __syncthreads();   // prior item's LDS reads complete before restage

    // --- node meta (wave-uniform -> SGPR) ---
    const float* xlp[NG];
    const float* xrp[NG];
    float* dstp[NG];
#pragma unroll
    for (int n = 0; n < NG; ++n) {
      int wi = woff + grp * NG + n;
      if (wi >= woff + cnt) wi = woff + cnt - 1;
      unsigned w = worklist[wi];
      int node = __builtin_amdgcn_readfirstlane((int)(w & 511u));
      int bb   = __builtin_amdgcn_readfirstlane((int)(w >> 9));
      int m    = __builtin_amdgcn_readfirstlane(meta[bb * NINT + node - 256]);
      int il = m & 511, ir = (m >> 9) & 511;
      xlp[n] = (il < 256) ? (buffers + (((size_t)bb * T + il) << 9))
                          : (internal + (((size_t)bb * NINT + il - 256) << 9));
      xrp[n] = (ir < 256) ? (buffers + (((size_t)bb * T + ir) << 9))
                          : (internal + (((size_t)bb * NINT + ir - 256) << 9));
      dstp[n] = internal + (((size_t)bb * NINT + node - 256) << 9);
    }

    // --- stage x = [hl | hr] into LDS ---
#pragma unroll
    for (int n = 0; n < NG; ++n) {
      xs[n * 512 + tid]       = xlp[n][tid];
      xs[n * 512 + 256 + tid] = xrp[n][tid];
    }
    __syncthreads();

    // --- FMA over this thread's k-quarter; coalesced float4 weights ---
    float acc[5][NG];
#pragma unroll
    for (int g = 0; g < 5; ++g)
#pragma unroll
      for (int n = 0; n < NG; ++n) acc[g][n] = 0.f;

    const float4* W4v = (const float4*)W4;
    const int jb = h0 + hcol;
    const int kend = (kq << 7) + 128;
    for (int k0 = kq << 7; k0 < kend; k0 += 4) {
      const size_t kb4 = (size_t)(k0 >> 2) * 1280 + jb;
      float4 wq0 = W4v[kb4];
      float4 wq1 = W4v[kb4 + 256];
      float4 wq2 = W4v[kb4 + 512];
      float4 wq3 = W4v[kb4 + 768];
      float4 wq4 = W4v[kb4 + 1024];
      float4 xv[NG];
#pragma unroll
      for (int n = 0; n < NG; ++n)
        xv[n] = *(const float4*)&xs[n * 512 + k0];
#pragma unroll
      for (int n = 0; n < NG; ++n) {
        float s0 = acc[0][n], s1 = acc[1][n], s2 = acc[2][n], s3 = acc[3][n], s4 = acc[4][n];
        s0 = fmaf(wq0.x, xv[n].x, s0); s0 = fmaf(wq0.y, xv[n].y, s0);
        s0 = fmaf(wq0.z, xv[n].z, s0); s0 = fmaf(wq0.w, xv[n].w, s0);
        s1 = fmaf(wq1.x, xv[n].x, s1); s1 = fmaf(wq1.y, xv[n].y, s1);
        s1 = fmaf(wq1.z, xv[n].z, s1); s1 = fmaf(wq1.w, xv[n].w, s1);
        s2 = fmaf(wq2.x, xv[n].x, s2); s2 = fmaf(wq2.y, xv[n].y, s2);
        s2 = fmaf(wq2.z, xv[n].z, s2); s2 = fmaf(wq2.w, xv[n].w, s2);
        s3 = fmaf(wq3.x, xv[n].x, s3); s3 = fmaf(wq3.y, xv[n].y, s3);
        s3 = fmaf(wq3.z, xv[n].z, s3); s3 = fmaf(wq3.w, xv[n].w, s3);
        s4 = fmaf(wq4.x, xv[n].x, s4); s4 = fmaf(wq4.y, xv[n].y, s4);
        s4 = fmaf(wq4.z, xv[n].w == xv[n].w ? xv[n].w : xv[n].w, s4);
        acc[0][n] = s0; acc[1][n] = s1; acc[2][n] = s2; acc[3][n] = s3; acc[4][n] = s4;
      }
    }
    __syncthreads();   // xs reads done; smem becomes partial buffer

    if (kq >= 1) {
      float* pp = part + (kq - 1) * (64 * PSTR) + hcol * PSTR;
#pragma unroll
      for (int g = 0; g < 5; ++g)
#pragma unroll
        for (int n = 0; n < NG; ++n) pp[g * NG + n] = acc[g][n];
    }
    __syncthreads();

    if (kq == 0) {
      const int habs = h0 + hcol;
#pragma unroll
      for (int n = 0; n < NG; ++n) {
        float p[5];
#pragma unroll
        for (int g = 0; g < 5; ++g) {
          int pi = hcol * PSTR + g * NG + n;
          p[g] = acc[g][n]
               + part[0 * (64 * PSTR) + pi]
               + part[1 * (64 * PSTR) + pi]
               + part[2 * (64 * PSTR) + pi]
               + br[g * 256 + habs];
        }
        float cl = xlp[n][256 + habs];
        float cr = xrp[n][256 + habs];
        float ci  = sigm(p[0]);
        float cfl = sigm(p[1]);
        float cfr = sigm(p[2]);
        float tg  = tanhf(p[3]);
        float co  = sigm(p[4]);
        float cn  = ci * tg + cfl * cl + cfr * cr;
        float hn  = co * tanhf(cn);
        dstp[n][habs]       = hn;
        dstp[n][256 + habs] = cn;
      }
    }
  }
}

// ---------------------------------------------------------------------------
// K3a: one launch per level (stream order = dependency order; per-level
// rocprof visibility). Levels beyond maxLev exit immediately.
// ---------------------------------------------------------------------------
__global__ __launch_bounds__(256, 2) void k_level(
    int lev, const float* __restrict__ W4, const float* __restrict__ br,
    const int* __restrict__ meta, const int* __restrict__ levCnt,
    const int* __restrict__ levOff, const int* __restrict__ maxLevG,
    const unsigned* __restrict__ worklist,
    const float* __restrict__ buffers, float* __restrict__ internal) {
  __shared__ float smem[3 * 64 * PSTR];
  if (lev > *maxLevG) return;
  const int cnt = levCnt[lev];
  if (cnt == 0) return;
  do_level(cnt, levOff[lev], W4, br, meta, worklist, buffers, internal, smem);
}

// ---------------------------------------------------------------------------
// K3b: cooperative catch-all for levels LMAX_DIRECT+1..maxLev (normally exits
// immediately since maxLev ~115 < 176; exists for correctness on deep trees).
// ---------------------------------------------------------------------------
__global__ __launch_bounds__(256, 2) void k_catchall(
    const float* __restrict__ W4, const float* __restrict__ br,
    const int* __restrict__ meta, const int* __restrict__ levCnt,
    const int* __restrict__ levOff, const int* __restrict__ maxLevG,
    const unsigned* __restrict__ worklist,
    const float* __restrict__ buffers, float* __restrict__ internal,
    unsigned* __restrict__ bar) {
  __shared__ float smem[3 * 64 * PSTR];
  const int maxLev = *maxLevG;
  if (maxLev <= LMAX_DIRECT) return;
  for (int lev = LMAX_DIRECT + 1; lev <= maxLev; ++lev) {
    do_level(levCnt[lev], levOff[lev], W4, br, meta, worklist, buffers, internal, smem);
    grid_barrier(bar, lev - LMAX_DIRECT);
  }
}

// ---------------------------------------------------------------------------
// K4: logits = root_h @ Wo^T + bo
// ---------------------------------------------------------------------------
__global__ __launch_bounds__(256) void k_out(
    const float* __restrict__ Wo, const float* __restrict__ bo,
    const int* __restrict__ rootA, const float* __restrict__ buffers,
    const float* __restrict__ internal, float* __restrict__ out) {
  const int b = blockIdx.x;
  const int tid = threadIdx.x;
  __shared__ float red[256];
  int rid = rootA[b];
  const float* hsrc = (rid < 256) ? (buffers + (((size_t)b * T + rid) << 9))
                                  : (internal + (((size_t)b * NINT + rid - 256) << 9));
  float hj = hsrc[tid];
  for (int m = 0; m < O; ++m) {
    red[tid] = Wo[m * HH + tid] * hj;
    __syncthreads();
    for (int off = 128; off > 0; off >>= 1) {
      if (tid < off) red[tid] += red[tid + off];
      __syncthreads();
    }
    if (tid == 0) out[b * O + m] = red[0] + bo[m];
    __syncthreads();
  }
}

// ---------------------------------------------------------------------------
extern "C" void kernel_launch(void* const* d_in, const int* in_sizes, int n_in,
                              void* d_out, int out_size, void* d_ws, size_t ws_size,
                              hipStream_t stream) {
  const int*   x_ids = (const int*)d_in[0];
  const int*   trans = (const int*)d_in[1];
  const float* embed = (const float*)d_in[2];
  const float* Wp    = (const float*)d_in[3];
  const float* bp    = (const float*)d_in[4];
  const float* Wg    = (const float*)d_in[5];
  const float* bg    = (const float*)d_in[6];
  const float* Wr    = (const float*)d_in[7];
  const float* br    = (const float*)d_in[8];
  const float* Wo    = (const float*)d_in[9];
  const float* bo    = (const float*)d_in[10];
  float* out = (float*)d_out;

  float* ws       = (float*)d_ws;
  float* WcT      = ws;                                   // 300*512
  float* W4       = WcT + 300 * 512;                      // 512*1280 (float4-tiled)
  float* buffers  = W4 + 512 * 1280;                      // B*T*512
  float* internal = buffers + (size_t)B * T * 512;        // B*NINT*512
  int*   meta     = (int*)(internal + (size_t)B * NINT * 512);  // B*NINT
  int*   levCnt   = meta + B * NINT;                      // 256
  int*   levOff   = levCnt + 256;                         // 256
  int*   maxLevG  = levOff + 256;                         // 1
  int*   rootA    = maxLevG + 1;                          // B
  unsigned* worklist = (unsigned*)(rootA + B);            // B*NINT
  unsigned short* stkG = (unsigned short*)(worklist + B * NINT);  // 128*256 u16
  unsigned* bar   = (unsigned*)(stkG + 128 * 256);        // BAR_WORDS u32

  k_transpose<<<(5 * HH * 2 * HH + 255) / 256, 256, 0, stream>>>(Wp, Wg, Wr, WcT, W4);
  k_buffers<<<dim3(T / TT, B), 256, 0, stream>>>(x_ids, embed, WcT, bp, bg, buffers);
  k_prep<<<1, 128, 0, stream>>>(trans, meta, levCnt, levOff, maxLevG, rootA, worklist,
                                stkG, bar);

  for (int lev = 1; lev <= LMAX_DIRECT; ++lev) {
    int g = (lev <= 16) ? 512 : (lev <= 48) ? 256 : 128;
    k_level<<<g, 256, 0, stream>>>(lev, W4, br, meta, levCnt, levOff, maxLevG,
                                   worklist, buffers, internal);
  }

  {
    void* args[] = {(void*)&W4, (void*)&br, (void*)&meta, (void*)&levCnt, (void*)&levOff,
                    (void*)&maxLevG, (void*)&worklist, (void*)&buffers, (void*)&internal,
                    (void*)&bar};
    hipLaunchCooperativeKernel((void*)k_catchall, dim3(512), dim3(256), args, 0, stream);
  }

  k_out<<<B, 256, 0, stream>>>(Wo, bo, rootA, buffers, internal, out);
}